// Round 7
// baseline (243.233 us; speedup 1.0000x reference)
//
#include <hip/hip_runtime.h>
#include <cstdint>
#include <cstddef>

#define NEG_SLOPE 0.2f

typedef __bf16 bf16x8 __attribute__((ext_vector_type(8)));
typedef float f32x4 __attribute__((ext_vector_type(4)));

static __device__ __forceinline__ unsigned short f2bf(float f) {
  unsigned int u = __float_as_uint(f);
  unsigned int r = (u + 0x7FFFu + ((u >> 16) & 1u)) >> 16;
  return (unsigned short)r;
}
static __device__ __forceinline__ float bf2f(unsigned short u) {
  return __uint_as_float(((unsigned int)u) << 16);
}
static __device__ __forceinline__ unsigned short f2h(float f) {
  _Float16 h = (_Float16)f;
  return __builtin_bit_cast(unsigned short, h);
}
static __device__ __forceinline__ float h2f(unsigned short u) {
  return (float)__builtin_bit_cast(_Float16, u);
}
static __device__ __forceinline__ float pklo(unsigned int x) {
  return __uint_as_float(x << 16);
}
static __device__ __forceinline__ float pkhi(unsigned int x) {
  return __uint_as_float(x & 0xffff0000u);
}

// ---------------- CSR build ----------------
__global__ void k_zero_i32(int* __restrict__ p, int n) {
  int i = blockIdx.x * 256 + threadIdx.x;
  if (i < n) p[i] = 0;
}

__global__ void k_degree(const int* __restrict__ ei, int* __restrict__ deg, int E) {
  int e = blockIdx.x * 256 + threadIdx.x;
  if (e < E) atomicAdd(&deg[ei[E + e]], 1);  // ei[E+e] = dst
}

__global__ __launch_bounds__(256) void k_scan_local(const int* __restrict__ deg,
                                                    int* __restrict__ lex,
                                                    int* __restrict__ bsum, int n) {
  __shared__ int ts[256];
  const int t = threadIdx.x;
  const int base = blockIdx.x * 1024 + t * 4;
  int4 d = {0, 0, 0, 0};
  if (base + 3 < n) d = *reinterpret_cast<const int4*>(&deg[base]);
  else {
    if (base + 0 < n) d.x = deg[base + 0];
    if (base + 1 < n) d.y = deg[base + 1];
    if (base + 2 < n) d.z = deg[base + 2];
  }
  int s = d.x + d.y + d.z + d.w;
  ts[t] = s;
  __syncthreads();
  for (int off = 1; off < 256; off <<= 1) {
    int y = (t >= off) ? ts[t - off] : 0;
    __syncthreads();
    ts[t] += y;
    __syncthreads();
  }
  int pre = ts[t] - s;
  int4 o;
  o.x = pre; o.y = pre + d.x; o.z = pre + d.x + d.y; o.w = pre + d.x + d.y + d.z;
  if (base + 3 < n) *reinterpret_cast<int4*>(&lex[base]) = o;
  else {
    if (base + 0 < n) lex[base + 0] = o.x;
    if (base + 1 < n) lex[base + 1] = o.y;
    if (base + 2 < n) lex[base + 2] = o.z;
  }
  if (t == 255) bsum[blockIdx.x] = ts[255];
}

__global__ __launch_bounds__(256) void k_scan_bsum(int* __restrict__ bsum, int nb) {
  __shared__ int ts[256];
  const int t = threadIdx.x;
  int v = (t < nb) ? bsum[t] : 0;
  ts[t] = v;
  __syncthreads();
  for (int off = 1; off < 256; off <<= 1) {
    int y = (t >= off) ? ts[t - off] : 0;
    __syncthreads();
    ts[t] += y;
    __syncthreads();
  }
  if (t < nb) bsum[t] = ts[t] - v;
}

__global__ void k_scan_add(const int* __restrict__ lex, const int* __restrict__ bsum,
                           int* __restrict__ rowptr, int* __restrict__ cursor,
                           int n, int E) {
  int i = blockIdx.x * 256 + threadIdx.x;
  if (i < n) {
    int v = lex[i] + bsum[i >> 10];
    rowptr[i] = v;
    cursor[i] = v;
  }
  if (i == n) rowptr[n] = E;
}

// col[pos] = src, dst_of[pos] = dst  (CSR slot -> endpoint ids)
__global__ void k_scatter(const int* __restrict__ ei, int* __restrict__ cursor,
                          int* __restrict__ col, int* __restrict__ dst_of, int E) {
  int e = blockIdx.x * 256 + threadIdx.x;
  if (e >= E) return;
  int d = ei[E + e];
  int pos = atomicAdd(&cursor[d], 1);
  col[pos] = ei[e];
  dst_of[pos] = d;
}

// ---------------- weight prep (all layers in one launch) ----------------
static __device__ __forceinline__ unsigned short pack_wt_elem(
    const float* __restrict__ Wl, const float* __restrict__ Ws,
    const float* __restrict__ Wd, const float* __restrict__ as_,
    const float* __restrict__ ad_, int t) {
  int j = t >> 7, k = t & 127;
  float val;
  if (j < 128) val = Wl[k * 128 + j];
  else if (j < 256) val = Ws[k * 128 + (j - 128)];
  else {
    int jj = j - 256;
    int h = jj & 7;
    const float* W = (jj < 8) ? Ws : Wd;
    const float* a = (jj < 8) ? as_ : ad_;
    float s = 0.f;
#pragma unroll
    for (int c = 0; c < 16; ++c) s += W[k * 128 + h * 16 + c] * a[h * 16 + c];
    val = s;
  }
  return f2bf(val);
}

__global__ void k_pack_all(
    const float* __restrict__ Wl0, const float* __restrict__ Ws0, const float* __restrict__ Wd0,
    const float* __restrict__ as0, const float* __restrict__ ad0,
    const float* __restrict__ Wl1, const float* __restrict__ Ws1, const float* __restrict__ Wd1,
    const float* __restrict__ as1, const float* __restrict__ ad1,
    const float* __restrict__ Wo,
    unsigned short* __restrict__ wt0, unsigned short* __restrict__ wt1,
    unsigned short* __restrict__ wot) {
  const int SZ = 272 * 128;
  int t = blockIdx.x * 256 + threadIdx.x;
  if (t < SZ) {
    wt0[t] = pack_wt_elem(Wl0, Ws0, Wd0, as0, ad0, t);
  } else if (t < 2 * SZ) {
    wt1[t - SZ] = pack_wt_elem(Wl1, Ws1, Wd1, as1, ad1, t - SZ);
  } else if (t < 2 * SZ + 64 * 128) {
    int u = t - 2 * SZ;
    int nn = u >> 7, k = u & 127;
    wot[u] = f2bf(Wo[k * 64 + nn]);
  }
}

// ---------------- persistent fused MFMA GEMM ----------------
// Outputs: ylin[N][128] f32 (+b_lin+b_conv folded), xsb[N][128] bf16,
// asd_s[N][8] bf16, asd_d[N][8] bf16 (all natural row-major). 8 waves.
template <typename TIN>
__global__ __launch_bounds__(512) void k_gemm_fused(
    const TIN* __restrict__ X, const unsigned short* __restrict__ wt,
    const float* __restrict__ bl, const float* __restrict__ bc,
    float* __restrict__ ylin, unsigned short* __restrict__ xsb,
    unsigned short* __restrict__ asd_s, unsigned short* __restrict__ asd_d,
    int n, int ntiles) {
  __shared__ __align__(16) unsigned short ws[272][136];
  __shared__ __align__(16) unsigned short xa[2][64][136];
  const int tid = threadIdx.x;

  for (int i = tid; i < 4352; i += 512) {   // stage ws once
    int r = i >> 4, ko = i & 15;
    *reinterpret_cast<uint4*>(&ws[r][ko * 8]) =
        reinterpret_cast<const uint4*>(wt)[(size_t)r * 16 + ko];
  }

  const int wave = tid >> 6, lane = tid & 63;
  const int gh = wave >> 2, fs = wave & 3;
  const int lr = lane & 15, lg = lane >> 4;
  const int f0 = fs * 4;
  const int nf = (fs == 3) ? 5 : 4;   // fs==3 also owns f=16 (asd)

  float4 rf[4];
  uint4 ru[2];
  int t = blockIdx.x;

#define LOAD_T(tt)                                                              \
  do {                                                                          \
    int row0_ = (tt) * 64;                                                      \
    if constexpr (sizeof(TIN) == 4) {                                           \
      _Pragma("unroll") for (int i = 0; i < 4; ++i) {                           \
        int c = tid + i * 512; int r = c >> 5, kq = c & 31;                     \
        rf[i] = make_float4(0.f, 0.f, 0.f, 0.f);                                \
        if (row0_ + r < n)                                                      \
          rf[i] = reinterpret_cast<const float4*>(X)[(size_t)(row0_ + r) * 32 + kq]; \
      }                                                                         \
    } else {                                                                    \
      _Pragma("unroll") for (int i = 0; i < 2; ++i) {                           \
        int c = tid + i * 512; int r = c >> 4, ko = c & 15;                     \
        ru[i] = uint4{0u, 0u, 0u, 0u};                                          \
        if (row0_ + r < n)                                                      \
          ru[i] = reinterpret_cast<const uint4*>(X)[(size_t)(row0_ + r) * 16 + ko]; \
      }                                                                         \
    }                                                                           \
  } while (0)

  LOAD_T(t);
  int buf = 0;
  for (; t < ntiles; t += gridDim.x) {
    if constexpr (sizeof(TIN) == 4) {
#pragma unroll
      for (int i = 0; i < 4; ++i) {
        int c = tid + i * 512; int r = c >> 5, kq = c & 31;
        ushort4 o;
        o.x = f2bf(rf[i].x); o.y = f2bf(rf[i].y); o.z = f2bf(rf[i].z); o.w = f2bf(rf[i].w);
        *reinterpret_cast<ushort4*>(&xa[buf][r][kq * 4]) = o;
      }
    } else {
#pragma unroll
      for (int i = 0; i < 2; ++i) {
        int c = tid + i * 512; int r = c >> 4, ko = c & 15;
        *reinterpret_cast<uint4*>(&xa[buf][r][ko * 8]) = ru[i];
      }
    }
    int tn = t + gridDim.x;
    if (tn < ntiles) LOAD_T(tn);   // issue next-tile loads early
    __syncthreads();

    const int row0 = t * 64;
    f32x4 acc[2][5];
#pragma unroll
    for (int g2 = 0; g2 < 2; ++g2)
#pragma unroll
      for (int ff = 0; ff < 5; ++ff) acc[g2][ff] = (f32x4){0.f, 0.f, 0.f, 0.f};

#pragma unroll
    for (int s = 0; s < 4; ++s) {
      bf16x8 a0 = *reinterpret_cast<const bf16x8*>(&xa[buf][gh * 32 + lr][s * 32 + lg * 8]);
      bf16x8 a1 = *reinterpret_cast<const bf16x8*>(&xa[buf][gh * 32 + 16 + lr][s * 32 + lg * 8]);
#pragma unroll
      for (int ff = 0; ff < 5; ++ff) {
        if (ff < nf) {
          int f = f0 + ff;
          bf16x8 b = *reinterpret_cast<const bf16x8*>(&ws[f * 16 + lr][s * 32 + lg * 8]);
          acc[0][ff] = __builtin_amdgcn_mfma_f32_16x16x32_bf16(a0, b, acc[0][ff], 0, 0, 0);
          acc[1][ff] = __builtin_amdgcn_mfma_f32_16x16x32_bf16(a1, b, acc[1][ff], 0, 0, 0);
        }
      }
    }

#pragma unroll
    for (int g2 = 0; g2 < 2; ++g2) {
      const int g = gh * 2 + g2;
#pragma unroll
      for (int ff = 0; ff < 5; ++ff) {
        if (ff < nf) {
          const int f = f0 + ff;
#pragma unroll
          for (int r = 0; r < 4; ++r) {
            int row = row0 + g * 16 + lg * 4 + r;
            if (row < n) {
              float v = acc[g2][ff][r];
              if (f < 8) {
                int j = f * 16 + lr;
                ylin[(size_t)row * 128 + j] = v + bl[j] + bc[j];
              } else if (f < 16) {
                xsb[(size_t)row * 128 + (f - 8) * 16 + lr] = f2bf(v);
              } else {
                if (lr < 8) asd_s[(size_t)row * 8 + lr] = f2bf(v);
                else        asd_d[(size_t)row * 8 + (lr - 8)] = f2bf(v);
              }
            }
          }
        }
      }
    }
    __syncthreads();
    buf ^= 1;
  }
#undef LOAD_T
}

// ---------------- final MFMA GEMM: out[N,64] = h@W_out + b (h bf16) ----------------
__global__ __launch_bounds__(256) void k_gemm_out(
    const unsigned short* __restrict__ X, const unsigned short* __restrict__ wo,
    const float* __restrict__ bias, float* __restrict__ out, int n) {
  __shared__ __align__(16) unsigned short xa[64][136];
  __shared__ __align__(16) unsigned short ws[64][136];
  const int tid = threadIdx.x;
  const int row0 = blockIdx.x * 64;

#pragma unroll
  for (int i = 0; i < 4; ++i) {
    int c = tid + i * 256;
    int r = c >> 4, ko = c & 15;
    uint4 v = {0u, 0u, 0u, 0u};
    if (row0 + r < n)
      v = reinterpret_cast<const uint4*>(X)[(size_t)(row0 + r) * 16 + ko];
    *reinterpret_cast<uint4*>(&xa[r][ko * 8]) = v;
  }
#pragma unroll
  for (int i = 0; i < 4; ++i) {
    int c = tid + i * 256;
    int r = c >> 4, ko = c & 15;
    *reinterpret_cast<uint4*>(&ws[r][ko * 8]) =
        reinterpret_cast<const uint4*>(wo)[(size_t)r * 16 + ko];
  }
  __syncthreads();

  const int w = tid >> 6, lane = tid & 63;
  const int lr = lane & 15, lg = lane >> 4;
  f32x4 acc[4];
#pragma unroll
  for (int f = 0; f < 4; ++f) acc[f] = (f32x4){0.f, 0.f, 0.f, 0.f};

#pragma unroll
  for (int s = 0; s < 4; ++s) {
    bf16x8 a = *reinterpret_cast<const bf16x8*>(&xa[w * 16 + lr][s * 32 + lg * 8]);
#pragma unroll
    for (int f = 0; f < 4; ++f) {
      bf16x8 b = *reinterpret_cast<const bf16x8*>(&ws[f * 16 + lr][s * 32 + lg * 8]);
      acc[f] = __builtin_amdgcn_mfma_f32_16x16x32_bf16(a, b, acc[f], 0, 0, 0);
    }
  }
#pragma unroll
  for (int f = 0; f < 4; ++f) {
#pragma unroll
    for (int r = 0; r < 4; ++r) {
      int row = row0 + w * 16 + lg * 4 + r;
      if (row < n)
        out[(size_t)row * 64 + f * 16 + lr] = acc[f][r] + bias[f * 16 + lr];
    }
  }
}

// ---------------- edge-parallel attention weights (CSR-slot order) ----------------
// lane t -> CSR slot pos = t>>3, head h = t&7.
// p[pos*8+h] = f16 exp(leaky(as[col[pos]] + ad[dst_of[pos]])) — same order
// k_aggregate consumes.
__global__ void k_edge(const int* __restrict__ col, const int* __restrict__ dst_of,
                       const unsigned short* __restrict__ asd_s,
                       const unsigned short* __restrict__ asd_d,
                       unsigned short* __restrict__ p, int E) {
  int t = blockIdx.x * 256 + threadIdx.x;
  if (t >= E * 8) return;
  int pos = t >> 3, h = t & 7;
  int src = col[pos], dst = dst_of[pos];
  float v = bf2f(asd_s[(size_t)src * 8 + h]) + bf2f(asd_d[(size_t)dst * 8 + h]);
  v = fmaxf(v, NEG_SLOPE * v);
  p[t] = f2h(__expf(v));
}

// ---------------- segment softmax aggregation + node update ----------------
// One wave per dst node; lane owns channels (2*lane, 2*lane+1), head h=lane>>3.
// p precomputed per (CSR slot, head); single-pass (no max-shift; logits O(1)).
__global__ __launch_bounds__(256) void k_aggregate(
    const float* __restrict__ ylin, const unsigned int* __restrict__ xsp,
    const unsigned short* __restrict__ p,
    const int* __restrict__ rowptr, const int* __restrict__ col,
    unsigned int* __restrict__ hout_pk, int n) {
  int node = (blockIdx.x * blockDim.x + threadIdx.x) >> 6;
  if (node >= n) return;
  const int lane = threadIdx.x & 63;
  const int h = lane >> 3;
  const int beg = rowptr[node], end = rowptr[node + 1];

  float dsum = 0.f, acc0 = 0.f, acc1 = 0.f;
  int e = beg;
  for (; e + 3 < end; e += 4) {
    int s0 = col[e], s1 = col[e + 1], s2 = col[e + 2], s3 = col[e + 3];
    float p0 = h2f(p[(size_t)(e + 0) * 8 + h]);
    float p1 = h2f(p[(size_t)(e + 1) * 8 + h]);
    float p2 = h2f(p[(size_t)(e + 2) * 8 + h]);
    float p3 = h2f(p[(size_t)(e + 3) * 8 + h]);
    unsigned int x0 = xsp[(size_t)s0 * 64 + lane];
    unsigned int x1 = xsp[(size_t)s1 * 64 + lane];
    unsigned int x2 = xsp[(size_t)s2 * 64 + lane];
    unsigned int x3 = xsp[(size_t)s3 * 64 + lane];
    dsum += (p0 + p1) + (p2 + p3);
    acc0 += p0 * pklo(x0) + p1 * pklo(x1) + p2 * pklo(x2) + p3 * pklo(x3);
    acc1 += p0 * pkhi(x0) + p1 * pkhi(x1) + p2 * pkhi(x2) + p3 * pkhi(x3);
  }
  for (; e < end; ++e) {
    int s0 = col[e];
    float p0 = h2f(p[(size_t)e * 8 + h]);
    unsigned int x0 = xsp[(size_t)s0 * 64 + lane];
    dsum += p0;
    acc0 += p0 * pklo(x0);
    acc1 += p0 * pkhi(x0);
  }
  float inv = 1.f / (dsum + 1e-16f);
  float2 y = reinterpret_cast<const float2*>(ylin)[(size_t)node * 64 + lane];
  float l0 = y.x + acc0 * inv;
  float l1 = y.y + acc1 * inv;
  l0 = l0 > 0.f ? l0 : __expf(l0) - 1.f;
  l1 = l1 > 0.f ? l1 : __expf(l1) - 1.f;
  hout_pk[(size_t)node * 64 + lane] =
      (unsigned int)f2bf(l0) | ((unsigned int)f2bf(l1) << 16);
}

// ---------------- launch ----------------
extern "C" void kernel_launch(void* const* d_in, const int* in_sizes, int n_in,
                              void* d_out, int out_size, void* d_ws, size_t ws_size,
                              hipStream_t stream) {
  const float* x      = (const float*)d_in[0];
  const int*   ei     = (const int*)d_in[1];
  const float* W_lin0 = (const float*)d_in[2];
  const float* b_lin0 = (const float*)d_in[3];
  const float* W_src0 = (const float*)d_in[4];
  const float* W_dst0 = (const float*)d_in[5];
  const float* att_s0 = (const float*)d_in[6];
  const float* att_d0 = (const float*)d_in[7];
  const float* b_cnv0 = (const float*)d_in[8];
  const float* W_lin1 = (const float*)d_in[9];
  const float* b_lin1 = (const float*)d_in[10];
  const float* W_src1 = (const float*)d_in[11];
  const float* W_dst1 = (const float*)d_in[12];
  const float* att_s1 = (const float*)d_in[13];
  const float* att_d1 = (const float*)d_in[14];
  const float* b_cnv1 = (const float*)d_in[15];
  const float* W_out  = (const float*)d_in[16];
  const float* b_out  = (const float*)d_in[17];
  float* out = (float*)d_out;

  const int N = in_sizes[0] / 128;
  const int E = in_sizes[1] / 2;
  const int NB = (N + 1023) / 1024;
  const int NTILES = (N + 63) / 64;

  char* p = (char*)d_ws;
  float* ylin           = (float*)p;          p += (size_t)N * 128 * 4;
  unsigned short* xsb   = (unsigned short*)p; p += (size_t)N * 128 * 2;
  unsigned short* hb    = (unsigned short*)p; p += (size_t)N * 128 * 2;
  unsigned short* asd_s = (unsigned short*)p; p += (size_t)N * 8 * 2;
  unsigned short* asd_d = (unsigned short*)p; p += (size_t)N * 8 * 2;
  unsigned short* pbuf  = (unsigned short*)p; p += (size_t)E * 8 * 2;
  unsigned short* wt0   = (unsigned short*)p; p += (size_t)272 * 128 * 2;
  unsigned short* wt1   = (unsigned short*)p; p += (size_t)272 * 128 * 2;
  unsigned short* wot   = (unsigned short*)p; p += (size_t)64 * 128 * 2;
  int* rowptr = (int*)p;                      p += (size_t)(N + 4) * 4;
  int* cursor = (int*)p;                      p += (size_t)N * 4;
  int* deg    = (int*)p;                      p += (size_t)N * 4;
  int* lex    = (int*)p;                      p += (size_t)N * 4;
  int* bsum   = (int*)p;                      p += (size_t)256 * 4;
  int* col    = (int*)p;                      p += (size_t)E * 4;
  int* dst_of = (int*)p;                      p += (size_t)E * 4;

  dim3 b256(256);

  // CSR by dst (shared by both layers)
  k_zero_i32<<<(N + 255) / 256, b256, 0, stream>>>(deg, N);
  k_degree<<<(E + 255) / 256, b256, 0, stream>>>(ei, deg, E);
  k_scan_local<<<NB, b256, 0, stream>>>(deg, lex, bsum, N);
  k_scan_bsum<<<1, b256, 0, stream>>>(bsum, NB);
  k_scan_add<<<(N + 256) / 256, b256, 0, stream>>>(lex, bsum, rowptr, cursor, N, E);
  k_scatter<<<(E + 255) / 256, b256, 0, stream>>>(ei, cursor, col, dst_of, E);

  // all weight packs in one launch
  k_pack_all<<<(2 * 272 * 128 + 64 * 128 + 255) / 256, b256, 0, stream>>>(
      W_lin0, W_src0, W_dst0, att_s0, att_d0,
      W_lin1, W_src1, W_dst1, att_s1, att_d1,
      W_out, wt0, wt1, wot);

  for (int layer = 0; layer < 2; ++layer) {
    const float* bl = layer ? b_lin1 : b_lin0;
    const float* bc = layer ? b_cnv1 : b_cnv0;
    const unsigned short* wt = layer ? wt1 : wt0;

    if (layer == 0)
      k_gemm_fused<float><<<256, 512, 0, stream>>>(x, wt, bl, bc, ylin, xsb,
                                                   asd_s, asd_d, N, NTILES);
    else
      k_gemm_fused<unsigned short><<<256, 512, 0, stream>>>(hb, wt, bl, bc, ylin, xsb,
                                                            asd_s, asd_d, N, NTILES);
    k_edge<<<(E * 8 + 255) / 256, b256, 0, stream>>>(col, dst_of, asd_s, asd_d, pbuf, E);
    k_aggregate<<<(N + 3) / 4, b256, 0, stream>>>(
        ylin, (const unsigned int*)xsb, pbuf, rowptr, col, (unsigned int*)hb, N);
  }
  k_gemm_out<<<(N + 63) / 64, b256, 0, stream>>>(hb, wot, b_out, out, N);
}